// Round 4
// baseline (88.102 us; speedup 1.0000x reference)
//
#include <hip/hip_runtime.h>
#include <float.h>

// Problem constants (from reference setup_inputs)
#define BB      2
#define CCH     256
#define HND     100
#define WND     100
#define NPTS    (HND * WND)   // 10000
#define NPOINT  9
#define NPTOT   (BB * NPTS * NPOINT)   // 180000 gather points
#define NBOX    (BB * NPTS)            // 20000 boxes
#define NXCD    8

// Gather grid geometry: 4 waves/block, 2 points/wave -> 8 points/block
#define GATHER_BLOCKS (NPTOT / 8)      // 22500 (exact)
#define BOX_BLOCKS    ((NBOX + 255) / 256)  // 79

// Native clang vector type — required by __builtin_nontemporal_*
typedef float f32x4 __attribute__((ext_vector_type(4)));

// Bijective XCD-chunked block swizzle (m204): consecutive WORK ids stay on
// the same XCD. Assumes dispatch round-robins blockIdx across 8 XCDs.
__device__ __forceinline__ int xcd_chunked(int bid, int nwg) {
    const int xcd = bid % NXCD, idx = bid / NXCD;
    const int q = nwg / NXCD, r = nwg % NXCD;
    const int base = (xcd < r) ? xcd * (q + 1) : r * (q + 1) + (xcd - r) * q;
    return base + idx;
}

// ---------------------------------------------------------------------------
// Kernel 1: transpose feat_map (B,C,H,W) -> (B,H*W,C).
// NT loads (read-once source) and NT stores (avoid per-XCD dirty lines in
// L2 that would be slow for other-XCD readers; data lands in L3).
// ---------------------------------------------------------------------------
__global__ __launch_bounds__(256)
void transpose_feat(const float* __restrict__ in, float* __restrict__ out) {
    __shared__ float tile[32][33];
    const int b    = blockIdx.z;
    const int col0 = blockIdx.x * 32;  // hw
    const int row0 = blockIdx.y * 32;  // c
    const int tx = threadIdx.x, ty = threadIdx.y;
    const float* src = in  + (size_t)b * CCH * NPTS;
    float*       dst = out + (size_t)b * NPTS * CCH;
#pragma unroll
    for (int i = 0; i < 4; ++i) {
        const int r   = row0 + ty + i * 8;   // channel (< 256 always)
        const int col = col0 + tx;           // hw
        if (col < NPTS)
            tile[ty + i * 8][tx] =
                __builtin_nontemporal_load(&src[(size_t)r * NPTS + col]);
    }
    __syncthreads();
#pragma unroll
    for (int i = 0; i < 4; ++i) {
        const int c2 = row0 + tx;            // channel
        const int hw = col0 + ty + i * 8;    // hw
        if (hw < NPTS)
            __builtin_nontemporal_store(tile[tx][ty + i * 8],
                                        &dst[(size_t)hw * CCH + c2]);
    }
}

// ---------------------------------------------------------------------------
// Bilinear weights/corners with the reference's exact boundary semantics
// (clamp at top edge, extrapolate below 0).
// ---------------------------------------------------------------------------
struct Bilin {
    int i1, i2, i3, i4;
    float w1, w2, w3, w4;
};

__device__ __forceinline__ Bilin bilin_setup(float w, float h) {
    Bilin r;
    const float h_low = fminf(fmaxf(floorf(h), 0.0f), (float)(HND - 1));
    const float w_low = fminf(fmaxf(floorf(w), 0.0f), (float)(WND - 1));
    const bool  hcap = (h_low >= (float)(HND - 1));
    const bool  wcap = (w_low >= (float)(WND - 1));
    const float h_high = hcap ? h_low : h_low + 1.0f;
    const float w_high = wcap ? w_low : w_low + 1.0f;
    const float he = hcap ? h_low : h;
    const float we = wcap ? w_low : w;
    const int hl  = (int)h_low,  wl  = (int)w_low;
    const int hhi = (int)h_high, whi = (int)w_high;
    const float lh = he - h_low, lw = we - w_low;
    const float hh = 1.0f - lh,  hw = 1.0f - lw;
    r.w1 = hh * hw; r.w2 = hh * lw; r.w3 = lh * hw; r.w4 = lh * lw;
    r.i1 = hl * WND + wl;  r.i2 = hl * WND + whi;
    r.i3 = hhi * WND + wl; r.i4 = hhi * WND + whi;
    return r;
}

// ---------------------------------------------------------------------------
// Kernel 2: deformable bilinear gather (+ fused boxes in trailing blocks).
// One wave handles TWO gather points; lane = 4 channels (f32x4).
// Gather blocks are XCD-chunk-swizzled: each XCD reads a contiguous ~2.6 MB
// slice of the transposed feat -> local-L2-resident.
// ---------------------------------------------------------------------------
__global__ __launch_bounds__(256)
void deform_gather_boxes(const float* __restrict__ feat,       // (B,HW,C)
                         const float* __restrict__ locations,  // (N,3)
                         const float* __restrict__ offset,     // (B,N,9,2)
                         const float* __restrict__ loc_pred,   // (B,N,18)
                         float* __restrict__ out_feats,        // (B,N,9,C)
                         float* __restrict__ out_boxes)        // (B,N,4)
{
    if (blockIdx.x < GATHER_BLOCKS) {
        const int gbid = xcd_chunked(blockIdx.x, GATHER_BLOCKS);
        const int wid  = threadIdx.x >> 6;
        const int lane = threadIdx.x & 63;
        const int p0 = (gbid * 4 + wid) * 2;
        const int p1 = p0 + 1;

        const int b0 = p0 / (NPTS * NPOINT);
        const int n0 = (p0 - b0 * (NPTS * NPOINT)) / NPOINT;
        const float w0f = (locations[n0 * 3 + 0] + (offset[(size_t)p0 * 2 + 0] * 64.0f) * 0.1f) * 0.125f;
        const float h0f = (locations[n0 * 3 + 1] + (offset[(size_t)p0 * 2 + 1] * 64.0f) * 0.1f) * 0.125f;
        const Bilin s0 = bilin_setup(w0f, h0f);
        const int b1 = p1 / (NPTS * NPOINT);
        const int n1 = (p1 - b1 * (NPTS * NPOINT)) / NPOINT;
        const float w1f = (locations[n1 * 3 + 0] + (offset[(size_t)p1 * 2 + 0] * 64.0f) * 0.1f) * 0.125f;
        const float h1f = (locations[n1 * 3 + 1] + (offset[(size_t)p1 * 2 + 1] * 64.0f) * 0.1f) * 0.125f;
        const Bilin s1 = bilin_setup(w1f, h1f);

        const float* base0 = feat + (size_t)b0 * NPTS * CCH;
        const float* base1 = feat + (size_t)b1 * NPTS * CCH;

        // 8 outstanding corner loads per wave.
        const f32x4 a0  = ((const f32x4*)(base0 + (size_t)s0.i1 * CCH))[lane];
        const f32x4 b0v = ((const f32x4*)(base0 + (size_t)s0.i2 * CCH))[lane];
        const f32x4 c0  = ((const f32x4*)(base0 + (size_t)s0.i3 * CCH))[lane];
        const f32x4 d0  = ((const f32x4*)(base0 + (size_t)s0.i4 * CCH))[lane];
        const f32x4 a1  = ((const f32x4*)(base1 + (size_t)s1.i1 * CCH))[lane];
        const f32x4 b1v = ((const f32x4*)(base1 + (size_t)s1.i2 * CCH))[lane];
        const f32x4 c1  = ((const f32x4*)(base1 + (size_t)s1.i3 * CCH))[lane];
        const f32x4 d1  = ((const f32x4*)(base1 + (size_t)s1.i4 * CCH))[lane];

        const f32x4 r0 = s0.w1 * a0 + s0.w2 * b0v + s0.w3 * c0 + s0.w4 * d0;
        const f32x4 r1 = s1.w1 * a1 + s1.w2 * b1v + s1.w3 * c1 + s1.w4 * d1;

        __builtin_nontemporal_store(r0, (f32x4*)(out_feats + (size_t)p0 * CCH) + lane);
        __builtin_nontemporal_store(r1, (f32x4*)(out_feats + (size_t)p1 * CCH) + lane);
    } else {
        // ----- boxes: one thread per (b,n) -----
        const int idx = (blockIdx.x - GATHER_BLOCKS) * 256 + threadIdx.x;
        if (idx >= NBOX) return;
        const int n = idx % NPTS;

        const float cx = locations[n * 3 + 0];
        const float cy = locations[n * 3 + 1];
        const float scale_ = locations[n * 3 + 2] * 8.0f;  // BASE_SCALE

        const float* off = offset   + (size_t)idx * (NPOINT * 2);
        const float* lp  = loc_pred + (size_t)idx * (NPOINT * 2);

        float xmin = FLT_MAX, ymin = FLT_MAX, xmax = -FLT_MAX, ymax = -FLT_MAX;
#pragma unroll
        for (int k = 0; k < NPOINT; ++k) {
            const float px = (cx + (off[2 * k    ] * scale_) * 0.1f) + (lp[2 * k    ] * scale_) * 0.5f;
            const float py = (cy + (off[2 * k + 1] * scale_) * 0.1f) + (lp[2 * k + 1] * scale_) * 0.5f;
            xmin = fminf(xmin, px); xmax = fmaxf(xmax, px);
            ymin = fminf(ymin, py); ymax = fmaxf(ymax, py);
        }
        f32x4 bx = { xmin, ymin, xmax, ymax };
        __builtin_nontemporal_store(bx, (f32x4*)(out_boxes + (size_t)idx * 4));
    }
}

// ---------------------------------------------------------------------------
// Fallback path (ws too small): gather direct from (B,C,H,W).
// ---------------------------------------------------------------------------
__global__ __launch_bounds__(256)
void deform_gather_direct(const float* __restrict__ feat,
                          const float* __restrict__ locations,
                          const float* __restrict__ offset,
                          float* __restrict__ out)
{
    const int wid  = threadIdx.x >> 6;
    const int lane = threadIdx.x & 63;
    const int pid  = blockIdx.x * 4 + wid;
    if (pid >= NPTOT) return;
    const int b   = pid / (NPTS * NPOINT);
    const int n   = (pid - b * (NPTS * NPOINT)) / NPOINT;
    const float w = (locations[n * 3 + 0] + (offset[(size_t)pid * 2 + 0] * 64.0f) * 0.1f) * 0.125f;
    const float h = (locations[n * 3 + 1] + (offset[(size_t)pid * 2 + 1] * 64.0f) * 0.1f) * 0.125f;
    const Bilin s = bilin_setup(w, h);
    const float* base = feat + (size_t)b * CCH * NPTS;
    float* o = out + (size_t)pid * CCH;
    for (int c = lane; c < CCH; c += 64) {
        const float* f = base + (size_t)c * NPTS;
        o[c] = s.w1 * f[s.i1] + s.w2 * f[s.i2] + s.w3 * f[s.i3] + s.w4 * f[s.i4];
    }
}

__global__ __launch_bounds__(256)
void boxes_kernel(const float* __restrict__ locations,
                  const float* __restrict__ offset,
                  const float* __restrict__ loc_pred,
                  float* __restrict__ out)
{
    const int idx = blockIdx.x * blockDim.x + threadIdx.x;
    if (idx >= NBOX) return;
    const int n = idx % NPTS;
    const float cx = locations[n * 3 + 0];
    const float cy = locations[n * 3 + 1];
    const float scale_ = locations[n * 3 + 2] * 8.0f;
    const float* off = offset   + (size_t)idx * (NPOINT * 2);
    const float* lp  = loc_pred + (size_t)idx * (NPOINT * 2);
    float xmin = FLT_MAX, ymin = FLT_MAX, xmax = -FLT_MAX, ymax = -FLT_MAX;
#pragma unroll
    for (int k = 0; k < NPOINT; ++k) {
        const float px = (cx + (off[2 * k    ] * scale_) * 0.1f) + (lp[2 * k    ] * scale_) * 0.5f;
        const float py = (cy + (off[2 * k + 1] * scale_) * 0.1f) + (lp[2 * k + 1] * scale_) * 0.5f;
        xmin = fminf(xmin, px); xmax = fmaxf(xmax, px);
        ymin = fminf(ymin, py); ymax = fmaxf(ymax, py);
    }
    float* ob = out + (size_t)idx * 4;
    ob[0] = xmin; ob[1] = ymin; ob[2] = xmax; ob[3] = ymax;
}

// ---------------------------------------------------------------------------
extern "C" void kernel_launch(void* const* d_in, const int* in_sizes, int n_in,
                              void* d_out, int out_size, void* d_ws, size_t ws_size,
                              hipStream_t stream) {
    const float* feat      = (const float*)d_in[0];
    const float* locations = (const float*)d_in[1];
    const float* offset    = (const float*)d_in[2];
    const float* loc_pred  = (const float*)d_in[3];
    float* out = (float*)d_out;

    const size_t deform_elems = (size_t)NPTOT * CCH;
    const size_t need_ws = (size_t)BB * NPTS * CCH * sizeof(float);

    if (ws_size >= need_ws) {
        dim3 tg((NPTS + 31) / 32, CCH / 32, BB);
        transpose_feat<<<tg, dim3(32, 8), 0, stream>>>(feat, (float*)d_ws);
        deform_gather_boxes<<<GATHER_BLOCKS + BOX_BLOCKS, 256, 0, stream>>>(
            (const float*)d_ws, locations, offset, loc_pred,
            out, out + deform_elems);
    } else {
        deform_gather_direct<<<(NPTOT + 3) / 4, 256, 0, stream>>>(
            feat, locations, offset, out);
        boxes_kernel<<<(NBOX + 255) / 256, 256, 0, stream>>>(
            locations, offset, loc_pred, out + deform_elems);
    }
}

// Round 5
// 51.933 us; speedup vs baseline: 1.6965x; 1.6965x over previous
//
#include <hip/hip_runtime.h>
#include <float.h>

// Problem constants (from reference setup_inputs)
#define BB      2
#define CCH     256
#define HND     100
#define WND     100
#define NPTS    (HND * WND)   // 10000
#define NPOINT  9
#define NPTOT   (BB * NPTS * NPOINT)   // 180000 gather points
#define NBOX    (BB * NPTS)            // 20000 boxes

// Gather grid geometry: 4 waves/block, 2 points/wave -> 8 points/block
#define GATHER_BLOCKS (NPTOT / 8)      // 22500 (exact)
#define BOX_BLOCKS    ((NBOX + 255) / 256)  // 79

// Native clang vector types (required by __builtin_nontemporal_store)
typedef float    f32x4 __attribute__((ext_vector_type(4)));
typedef unsigned u32x2 __attribute__((ext_vector_type(2)));

// f32 -> bf16 with round-to-nearest-even
__device__ __forceinline__ unsigned short f2bf(float f) {
    unsigned u = __float_as_uint(f);
    return (unsigned short)((u + 0x7FFFu + ((u >> 16) & 1u)) >> 16);
}

// ---------------------------------------------------------------------------
// Kernel 1: transpose+downconvert feat_map (B,C,H,W) f32 -> (B,H*W,C) bf16.
// 32x32 LDS tile (padded, conflict-free). Store phase packs 4 channels into
// one uint2 (8 B) per thread -> coalesced 64 B runs. Plain (cached) stores:
// the gather reads this immediately, keep it in L2.
// ---------------------------------------------------------------------------
__global__ __launch_bounds__(256)
void transpose_feat_bf16(const float* __restrict__ in,
                         unsigned short* __restrict__ out) {
    __shared__ float tile[32][33];   // [c_local][hw_local]
    const int b    = blockIdx.z;
    const int col0 = blockIdx.x * 32;  // hw
    const int row0 = blockIdx.y * 32;  // c
    const int tx = threadIdx.x, ty = threadIdx.y;
    const float* src = in + (size_t)b * CCH * NPTS;
#pragma unroll
    for (int i = 0; i < 4; ++i) {
        const int c   = row0 + ty + i * 8;   // channel (< 256 always)
        const int col = col0 + tx;           // hw
        if (col < NPTS)
            tile[ty + i * 8][tx] = src[(size_t)c * NPTS + col];
    }
    __syncthreads();
    // Store: one uint2 (4 bf16 channels) per thread; 8 quads x 32 hw = 256.
    const int tid     = ty * 32 + tx;
    const int c_quad  = tid & 7;        // 0..7  -> channels 4q..4q+3 of tile
    const int hw_loc  = tid >> 3;       // 0..31
    const int hw      = col0 + hw_loc;
    if (hw < NPTS) {
        u32x2 v;
        const float f0 = tile[4 * c_quad + 0][hw_loc];
        const float f1 = tile[4 * c_quad + 1][hw_loc];
        const float f2 = tile[4 * c_quad + 2][hw_loc];
        const float f3 = tile[4 * c_quad + 3][hw_loc];
        v.x = (unsigned)f2bf(f0) | ((unsigned)f2bf(f1) << 16);
        v.y = (unsigned)f2bf(f2) | ((unsigned)f2bf(f3) << 16);
        u32x2* dst = (u32x2*)(out + (size_t)b * NPTS * CCH);
        dst[(size_t)hw * (CCH / 4) + (row0 >> 2) + c_quad] = v;
    }
}

// ---------------------------------------------------------------------------
// Bilinear weights/corners with the reference's exact boundary semantics
// (clamp at top edge, extrapolate below 0).
// ---------------------------------------------------------------------------
struct Bilin {
    int i1, i2, i3, i4;
    float w1, w2, w3, w4;
};

__device__ __forceinline__ Bilin bilin_setup(float w, float h) {
    Bilin r;
    const float h_low = fminf(fmaxf(floorf(h), 0.0f), (float)(HND - 1));
    const float w_low = fminf(fmaxf(floorf(w), 0.0f), (float)(WND - 1));
    const bool  hcap = (h_low >= (float)(HND - 1));
    const bool  wcap = (w_low >= (float)(WND - 1));
    const float h_high = hcap ? h_low : h_low + 1.0f;
    const float w_high = wcap ? w_low : w_low + 1.0f;
    const float he = hcap ? h_low : h;
    const float we = wcap ? w_low : w;
    const int hl  = (int)h_low,  wl  = (int)w_low;
    const int hhi = (int)h_high, whi = (int)w_high;
    const float lh = he - h_low, lw = we - w_low;
    const float hh = 1.0f - lh,  hw = 1.0f - lw;
    r.w1 = hh * hw; r.w2 = hh * lw; r.w3 = lh * hw; r.w4 = lh * lw;
    r.i1 = hl * WND + wl;  r.i2 = hl * WND + whi;
    r.i3 = hhi * WND + wl; r.i4 = hhi * WND + whi;
    return r;
}

// Unpack 4 bf16 channels (one uint2) to 4 f32.
__device__ __forceinline__ f32x4 unpack_bf4(u32x2 v) {
    f32x4 f;
    f.x = __uint_as_float(v.x << 16);
    f.y = __uint_as_float(v.x & 0xFFFF0000u);
    f.z = __uint_as_float(v.y << 16);
    f.w = __uint_as_float(v.y & 0xFFFF0000u);
    return f;
}

// ---------------------------------------------------------------------------
// Kernel 2: deformable bilinear gather (+ fused boxes in trailing blocks).
// One wave handles TWO gather points; lane = 4 channels. Corner reads are
// bf16 (8 B/lane, 512 B/corner/wave). Output f32, non-temporal full-line
// stores (write-once stream must not evict feat from L2).
// ---------------------------------------------------------------------------
__global__ __launch_bounds__(256)
void deform_gather_boxes(const unsigned short* __restrict__ feat, // (B,HW,C) bf16
                         const float* __restrict__ locations,     // (N,3)
                         const float* __restrict__ offset,        // (B,N,9,2)
                         const float* __restrict__ loc_pred,      // (B,N,18)
                         float* __restrict__ out_feats,           // (B,N,9,C)
                         float* __restrict__ out_boxes)           // (B,N,4)
{
    if (blockIdx.x < GATHER_BLOCKS) {
        const int wid  = threadIdx.x >> 6;
        const int lane = threadIdx.x & 63;
        const int p0 = (blockIdx.x * 4 + wid) * 2;
        const int p1 = p0 + 1;

        const int b0 = p0 / (NPTS * NPOINT);
        const int n0 = (p0 - b0 * (NPTS * NPOINT)) / NPOINT;
        const float w0f = (locations[n0 * 3 + 0] + (offset[(size_t)p0 * 2 + 0] * 64.0f) * 0.1f) * 0.125f;
        const float h0f = (locations[n0 * 3 + 1] + (offset[(size_t)p0 * 2 + 1] * 64.0f) * 0.1f) * 0.125f;
        const Bilin s0 = bilin_setup(w0f, h0f);
        const int b1 = p1 / (NPTS * NPOINT);
        const int n1 = (p1 - b1 * (NPTS * NPOINT)) / NPOINT;
        const float w1f = (locations[n1 * 3 + 0] + (offset[(size_t)p1 * 2 + 0] * 64.0f) * 0.1f) * 0.125f;
        const float h1f = (locations[n1 * 3 + 1] + (offset[(size_t)p1 * 2 + 1] * 64.0f) * 0.1f) * 0.125f;
        const Bilin s1 = bilin_setup(w1f, h1f);

        const u32x2* base0 = (const u32x2*)(feat + (size_t)b0 * NPTS * CCH);
        const u32x2* base1 = (const u32x2*)(feat + (size_t)b1 * NPTS * CCH);

        // 8 outstanding corner loads per wave (8 B/lane each).
        const u32x2 a0  = base0[(size_t)s0.i1 * (CCH / 4) + lane];
        const u32x2 b0v = base0[(size_t)s0.i2 * (CCH / 4) + lane];
        const u32x2 c0  = base0[(size_t)s0.i3 * (CCH / 4) + lane];
        const u32x2 d0  = base0[(size_t)s0.i4 * (CCH / 4) + lane];
        const u32x2 a1  = base1[(size_t)s1.i1 * (CCH / 4) + lane];
        const u32x2 b1v = base1[(size_t)s1.i2 * (CCH / 4) + lane];
        const u32x2 c1  = base1[(size_t)s1.i3 * (CCH / 4) + lane];
        const u32x2 d1  = base1[(size_t)s1.i4 * (CCH / 4) + lane];

        const f32x4 r0 = s0.w1 * unpack_bf4(a0) + s0.w2 * unpack_bf4(b0v)
                       + s0.w3 * unpack_bf4(c0) + s0.w4 * unpack_bf4(d0);
        const f32x4 r1 = s1.w1 * unpack_bf4(a1) + s1.w2 * unpack_bf4(b1v)
                       + s1.w3 * unpack_bf4(c1) + s1.w4 * unpack_bf4(d1);

        __builtin_nontemporal_store(r0, (f32x4*)(out_feats + (size_t)p0 * CCH) + lane);
        __builtin_nontemporal_store(r1, (f32x4*)(out_feats + (size_t)p1 * CCH) + lane);
    } else {
        // ----- boxes: one thread per (b,n) -----
        const int idx = (blockIdx.x - GATHER_BLOCKS) * 256 + threadIdx.x;
        if (idx >= NBOX) return;
        const int n = idx % NPTS;

        const float cx = locations[n * 3 + 0];
        const float cy = locations[n * 3 + 1];
        const float scale_ = locations[n * 3 + 2] * 8.0f;  // BASE_SCALE

        const float* off = offset   + (size_t)idx * (NPOINT * 2);
        const float* lp  = loc_pred + (size_t)idx * (NPOINT * 2);

        float xmin = FLT_MAX, ymin = FLT_MAX, xmax = -FLT_MAX, ymax = -FLT_MAX;
#pragma unroll
        for (int k = 0; k < NPOINT; ++k) {
            const float px = (cx + (off[2 * k    ] * scale_) * 0.1f) + (lp[2 * k    ] * scale_) * 0.5f;
            const float py = (cy + (off[2 * k + 1] * scale_) * 0.1f) + (lp[2 * k + 1] * scale_) * 0.5f;
            xmin = fminf(xmin, px); xmax = fmaxf(xmax, px);
            ymin = fminf(ymin, py); ymax = fmaxf(ymax, py);
        }
        f32x4 bx = { xmin, ymin, xmax, ymax };
        __builtin_nontemporal_store(bx, (f32x4*)(out_boxes + (size_t)idx * 4));
    }
}

// ---------------------------------------------------------------------------
// Fallback path (ws too small): gather direct from (B,C,H,W) f32.
// ---------------------------------------------------------------------------
__global__ __launch_bounds__(256)
void deform_gather_direct(const float* __restrict__ feat,
                          const float* __restrict__ locations,
                          const float* __restrict__ offset,
                          float* __restrict__ out)
{
    const int wid  = threadIdx.x >> 6;
    const int lane = threadIdx.x & 63;
    const int pid  = blockIdx.x * 4 + wid;
    if (pid >= NPTOT) return;
    const int b   = pid / (NPTS * NPOINT);
    const int n   = (pid - b * (NPTS * NPOINT)) / NPOINT;
    const float w = (locations[n * 3 + 0] + (offset[(size_t)pid * 2 + 0] * 64.0f) * 0.1f) * 0.125f;
    const float h = (locations[n * 3 + 1] + (offset[(size_t)pid * 2 + 1] * 64.0f) * 0.1f) * 0.125f;
    const Bilin s = bilin_setup(w, h);
    const float* base = feat + (size_t)b * CCH * NPTS;
    float* o = out + (size_t)pid * CCH;
    for (int c = lane; c < CCH; c += 64) {
        const float* f = base + (size_t)c * NPTS;
        o[c] = s.w1 * f[s.i1] + s.w2 * f[s.i2] + s.w3 * f[s.i3] + s.w4 * f[s.i4];
    }
}

__global__ __launch_bounds__(256)
void boxes_kernel(const float* __restrict__ locations,
                  const float* __restrict__ offset,
                  const float* __restrict__ loc_pred,
                  float* __restrict__ out)
{
    const int idx = blockIdx.x * blockDim.x + threadIdx.x;
    if (idx >= NBOX) return;
    const int n = idx % NPTS;
    const float cx = locations[n * 3 + 0];
    const float cy = locations[n * 3 + 1];
    const float scale_ = locations[n * 3 + 2] * 8.0f;
    const float* off = offset   + (size_t)idx * (NPOINT * 2);
    const float* lp  = loc_pred + (size_t)idx * (NPOINT * 2);
    float xmin = FLT_MAX, ymin = FLT_MAX, xmax = -FLT_MAX, ymax = -FLT_MAX;
#pragma unroll
    for (int k = 0; k < NPOINT; ++k) {
        const float px = (cx + (off[2 * k    ] * scale_) * 0.1f) + (lp[2 * k    ] * scale_) * 0.5f;
        const float py = (cy + (off[2 * k + 1] * scale_) * 0.1f) + (lp[2 * k + 1] * scale_) * 0.5f;
        xmin = fminf(xmin, px); xmax = fmaxf(xmax, px);
        ymin = fminf(ymin, py); ymax = fmaxf(ymax, py);
    }
    float* ob = out + (size_t)idx * 4;
    ob[0] = xmin; ob[1] = ymin; ob[2] = xmax; ob[3] = ymax;
}

// ---------------------------------------------------------------------------
extern "C" void kernel_launch(void* const* d_in, const int* in_sizes, int n_in,
                              void* d_out, int out_size, void* d_ws, size_t ws_size,
                              hipStream_t stream) {
    const float* feat      = (const float*)d_in[0];
    const float* locations = (const float*)d_in[1];
    const float* offset    = (const float*)d_in[2];
    const float* loc_pred  = (const float*)d_in[3];
    float* out = (float*)d_out;

    const size_t deform_elems = (size_t)NPTOT * CCH;
    const size_t need_ws = (size_t)BB * NPTS * CCH * sizeof(unsigned short);

    if (ws_size >= need_ws) {
        dim3 tg((NPTS + 31) / 32, CCH / 32, BB);
        transpose_feat_bf16<<<tg, dim3(32, 8), 0, stream>>>(
            feat, (unsigned short*)d_ws);
        deform_gather_boxes<<<GATHER_BLOCKS + BOX_BLOCKS, 256, 0, stream>>>(
            (const unsigned short*)d_ws, locations, offset, loc_pred,
            out, out + deform_elems);
    } else {
        deform_gather_direct<<<(NPTOT + 3) / 4, 256, 0, stream>>>(
            feat, locations, offset, out);
        boxes_kernel<<<(NBOX + 255) / 256, 256, 0, stream>>>(
            locations, offset, loc_pred, out + deform_elems);
    }
}

// Round 6
// 51.319 us; speedup vs baseline: 1.7167x; 1.0120x over previous
//
#include <hip/hip_runtime.h>
#include <float.h>

// Problem constants (from reference setup_inputs)
#define BB      2
#define CCH     256
#define HND     100
#define WND     100
#define NPTS    (HND * WND)   // 10000
#define NPOINT  9
#define NPTOT   (BB * NPTS * NPOINT)   // 180000 gather points
#define NBOX    (BB * NPTS)            // 20000 boxes

// Gather grid geometry: 4 waves/block, 4 points/wave -> 16 points/block
#define GATHER_BLOCKS (NPTOT / 16)     // 11250 (exact)
#define BOX_BLOCKS    ((NBOX + 255) / 256)  // 79

// Native clang vector types (required by __builtin_nontemporal_store)
typedef float    f32x4 __attribute__((ext_vector_type(4)));
typedef unsigned u32x2 __attribute__((ext_vector_type(2)));

// f32 -> bf16 with round-to-nearest-even
__device__ __forceinline__ unsigned short f2bf(float f) {
    unsigned u = __float_as_uint(f);
    return (unsigned short)((u + 0x7FFFu + ((u >> 16) & 1u)) >> 16);
}

// ---------------------------------------------------------------------------
// Kernel 1: transpose+downconvert feat_map (B,C,H,W) f32 -> (B,H*W,C) bf16.
// 32x32 LDS tile (padded, conflict-free). Store packs 4 channels into one
// uint2 (8 B)/thread -> coalesced 512 B runs per wave. Plain cached stores
// (gather reads this immediately; NT scalar stores regressed in R4).
// ---------------------------------------------------------------------------
__global__ __launch_bounds__(256)
void transpose_feat_bf16(const float* __restrict__ in,
                         unsigned short* __restrict__ out) {
    __shared__ float tile[32][33];   // [c_local][hw_local]
    const int b    = blockIdx.z;
    const int col0 = blockIdx.x * 32;  // hw
    const int row0 = blockIdx.y * 32;  // c
    const int tx = threadIdx.x, ty = threadIdx.y;
    const float* src = in + (size_t)b * CCH * NPTS;
#pragma unroll
    for (int i = 0; i < 4; ++i) {
        const int c   = row0 + ty + i * 8;   // channel (< 256 always)
        const int col = col0 + tx;           // hw
        if (col < NPTS)
            tile[ty + i * 8][tx] = src[(size_t)c * NPTS + col];
    }
    __syncthreads();
    // Store: one uint2 (4 bf16 channels) per thread; 8 quads x 32 hw = 256.
    const int tid     = ty * 32 + tx;
    const int c_quad  = tid & 7;        // 0..7  -> channels 4q..4q+3 of tile
    const int hw_loc  = tid >> 3;       // 0..31
    const int hw      = col0 + hw_loc;
    if (hw < NPTS) {
        u32x2 v;
        const float f0 = tile[4 * c_quad + 0][hw_loc];
        const float f1 = tile[4 * c_quad + 1][hw_loc];
        const float f2 = tile[4 * c_quad + 2][hw_loc];
        const float f3 = tile[4 * c_quad + 3][hw_loc];
        v.x = (unsigned)f2bf(f0) | ((unsigned)f2bf(f1) << 16);
        v.y = (unsigned)f2bf(f2) | ((unsigned)f2bf(f3) << 16);
        u32x2* dst = (u32x2*)(out + (size_t)b * NPTS * CCH);
        dst[(size_t)hw * (CCH / 4) + (row0 >> 2) + c_quad] = v;
    }
}

// ---------------------------------------------------------------------------
// Bilinear weights/corners with the reference's exact boundary semantics
// (clamp at top edge, extrapolate below 0).
// ---------------------------------------------------------------------------
struct Bilin {
    int i1, i2, i3, i4;
    float w1, w2, w3, w4;
};

__device__ __forceinline__ Bilin bilin_setup(float w, float h) {
    Bilin r;
    const float h_low = fminf(fmaxf(floorf(h), 0.0f), (float)(HND - 1));
    const float w_low = fminf(fmaxf(floorf(w), 0.0f), (float)(WND - 1));
    const bool  hcap = (h_low >= (float)(HND - 1));
    const bool  wcap = (w_low >= (float)(WND - 1));
    const float he = hcap ? h_low : h;
    const float we = wcap ? w_low : w;
    const int hl  = (int)h_low,  wl  = (int)w_low;
    const int hhi = hcap ? hl : hl + 1;
    const int whi = wcap ? wl : wl + 1;
    const float lh = he - h_low, lw = we - w_low;
    const float hh = 1.0f - lh,  hw = 1.0f - lw;
    r.w1 = hh * hw; r.w2 = hh * lw; r.w3 = lh * hw; r.w4 = lh * lw;
    r.i1 = hl * WND + wl;  r.i2 = hl * WND + whi;
    r.i3 = hhi * WND + wl; r.i4 = hhi * WND + whi;
    return r;
}

// Unpack 4 bf16 channels (one uint2) to 4 f32.
__device__ __forceinline__ f32x4 unpack_bf4(u32x2 v) {
    f32x4 f;
    f.x = __uint_as_float(v.x << 16);
    f.y = __uint_as_float(v.x & 0xFFFF0000u);
    f.z = __uint_as_float(v.y << 16);
    f.w = __uint_as_float(v.y & 0xFFFF0000u);
    return f;
}

// ---------------------------------------------------------------------------
// Kernel 2: deformable bilinear gather (+ fused boxes in trailing blocks).
// One wave handles FOUR gather points; lane = 4 channels. All 16 corner
// loads (8 B/lane) issued before any FMA -> deep MLP; address math amortized
// over 4 KB of output per wave. Output f32, NT full-line stores.
// ---------------------------------------------------------------------------
__global__ __launch_bounds__(256)
void deform_gather_boxes(const unsigned short* __restrict__ feat, // (B,HW,C) bf16
                         const float* __restrict__ locations,     // (N,3)
                         const float* __restrict__ offset,        // (B,N,9,2)
                         const float* __restrict__ loc_pred,      // (B,N,18)
                         float* __restrict__ out_feats,           // (B,N,9,C)
                         float* __restrict__ out_boxes)           // (B,N,4)
{
    if (blockIdx.x < GATHER_BLOCKS) {
        const int wid  = threadIdx.x >> 6;
        const int lane = threadIdx.x & 63;
        const int pb   = (blockIdx.x * 4 + wid) * 4;   // 4 consecutive points

        // Phase 1: per-point bilinear setup (static-index arrays, unrolled).
        Bilin s[4];
        const u32x2* base[4];
#pragma unroll
        for (int k = 0; k < 4; ++k) {
            const int p = pb + k;
            const int b = p / (NPTS * NPOINT);
            const int n = (p - b * (NPTS * NPOINT)) / NPOINT;
            const float wf = (locations[n * 3 + 0] + (offset[(size_t)p * 2 + 0] * 64.0f) * 0.1f) * 0.125f;
            const float hf = (locations[n * 3 + 1] + (offset[(size_t)p * 2 + 1] * 64.0f) * 0.1f) * 0.125f;
            s[k] = bilin_setup(wf, hf);
            base[k] = (const u32x2*)(feat + (size_t)b * NPTS * CCH);
        }

        // Phase 2: issue all 16 corner loads (16 outstanding vmem / wave).
        u32x2 v1[4], v2[4], v3[4], v4[4];
#pragma unroll
        for (int k = 0; k < 4; ++k) {
            v1[k] = base[k][(size_t)s[k].i1 * (CCH / 4) + lane];
            v2[k] = base[k][(size_t)s[k].i2 * (CCH / 4) + lane];
            v3[k] = base[k][(size_t)s[k].i3 * (CCH / 4) + lane];
            v4[k] = base[k][(size_t)s[k].i4 * (CCH / 4) + lane];
        }

        // Phase 3: combine + NT store (1 KB/point, full lines).
#pragma unroll
        for (int k = 0; k < 4; ++k) {
            const f32x4 r = s[k].w1 * unpack_bf4(v1[k]) + s[k].w2 * unpack_bf4(v2[k])
                          + s[k].w3 * unpack_bf4(v3[k]) + s[k].w4 * unpack_bf4(v4[k]);
            __builtin_nontemporal_store(r, (f32x4*)(out_feats + (size_t)(pb + k) * CCH) + lane);
        }
    } else {
        // ----- boxes: one thread per (b,n) -----
        const int idx = (blockIdx.x - GATHER_BLOCKS) * 256 + threadIdx.x;
        if (idx >= NBOX) return;
        const int n = idx % NPTS;

        const float cx = locations[n * 3 + 0];
        const float cy = locations[n * 3 + 1];
        const float scale_ = locations[n * 3 + 2] * 8.0f;  // BASE_SCALE

        const float* off = offset   + (size_t)idx * (NPOINT * 2);
        const float* lp  = loc_pred + (size_t)idx * (NPOINT * 2);

        float xmin = FLT_MAX, ymin = FLT_MAX, xmax = -FLT_MAX, ymax = -FLT_MAX;
#pragma unroll
        for (int k = 0; k < NPOINT; ++k) {
            const float px = (cx + (off[2 * k    ] * scale_) * 0.1f) + (lp[2 * k    ] * scale_) * 0.5f;
            const float py = (cy + (off[2 * k + 1] * scale_) * 0.1f) + (lp[2 * k + 1] * scale_) * 0.5f;
            xmin = fminf(xmin, px); xmax = fmaxf(xmax, px);
            ymin = fminf(ymin, py); ymax = fmaxf(ymax, py);
        }
        f32x4 bx = { xmin, ymin, xmax, ymax };
        __builtin_nontemporal_store(bx, (f32x4*)(out_boxes + (size_t)idx * 4));
    }
}

// ---------------------------------------------------------------------------
// Fallback path (ws too small): gather direct from (B,C,H,W) f32.
// ---------------------------------------------------------------------------
__global__ __launch_bounds__(256)
void deform_gather_direct(const float* __restrict__ feat,
                          const float* __restrict__ locations,
                          const float* __restrict__ offset,
                          float* __restrict__ out)
{
    const int wid  = threadIdx.x >> 6;
    const int lane = threadIdx.x & 63;
    const int pid  = blockIdx.x * 4 + wid;
    if (pid >= NPTOT) return;
    const int b   = pid / (NPTS * NPOINT);
    const int n   = (pid - b * (NPTS * NPOINT)) / NPOINT;
    const float w = (locations[n * 3 + 0] + (offset[(size_t)pid * 2 + 0] * 64.0f) * 0.1f) * 0.125f;
    const float h = (locations[n * 3 + 1] + (offset[(size_t)pid * 2 + 1] * 64.0f) * 0.1f) * 0.125f;
    const Bilin s = bilin_setup(w, h);
    const float* base = feat + (size_t)b * CCH * NPTS;
    float* o = out + (size_t)pid * CCH;
    for (int c = lane; c < CCH; c += 64) {
        const float* f = base + (size_t)c * NPTS;
        o[c] = s.w1 * f[s.i1] + s.w2 * f[s.i2] + s.w3 * f[s.i3] + s.w4 * f[s.i4];
    }
}

__global__ __launch_bounds__(256)
void boxes_kernel(const float* __restrict__ locations,
                  const float* __restrict__ offset,
                  const float* __restrict__ loc_pred,
                  float* __restrict__ out)
{
    const int idx = blockIdx.x * blockDim.x + threadIdx.x;
    if (idx >= NBOX) return;
    const int n = idx % NPTS;
    const float cx = locations[n * 3 + 0];
    const float cy = locations[n * 3 + 1];
    const float scale_ = locations[n * 3 + 2] * 8.0f;
    const float* off = offset   + (size_t)idx * (NPOINT * 2);
    const float* lp  = loc_pred + (size_t)idx * (NPOINT * 2);
    float xmin = FLT_MAX, ymin = FLT_MAX, xmax = -FLT_MAX, ymax = -FLT_MAX;
#pragma unroll
    for (int k = 0; k < NPOINT; ++k) {
        const float px = (cx + (off[2 * k    ] * scale_) * 0.1f) + (lp[2 * k    ] * scale_) * 0.5f;
        const float py = (cy + (off[2 * k + 1] * scale_) * 0.1f) + (lp[2 * k + 1] * scale_) * 0.5f;
        xmin = fminf(xmin, px); xmax = fmaxf(xmax, px);
        ymin = fminf(ymin, py); ymax = fmaxf(ymax, py);
    }
    float* ob = out + (size_t)idx * 4;
    ob[0] = xmin; ob[1] = ymin; ob[2] = xmax; ob[3] = ymax;
}

// ---------------------------------------------------------------------------
extern "C" void kernel_launch(void* const* d_in, const int* in_sizes, int n_in,
                              void* d_out, int out_size, void* d_ws, size_t ws_size,
                              hipStream_t stream) {
    const float* feat      = (const float*)d_in[0];
    const float* locations = (const float*)d_in[1];
    const float* offset    = (const float*)d_in[2];
    const float* loc_pred  = (const float*)d_in[3];
    float* out = (float*)d_out;

    const size_t deform_elems = (size_t)NPTOT * CCH;
    const size_t need_ws = (size_t)BB * NPTS * CCH * sizeof(unsigned short);

    if (ws_size >= need_ws) {
        dim3 tg((NPTS + 31) / 32, CCH / 32, BB);
        transpose_feat_bf16<<<tg, dim3(32, 8), 0, stream>>>(
            feat, (unsigned short*)d_ws);
        deform_gather_boxes<<<GATHER_BLOCKS + BOX_BLOCKS, 256, 0, stream>>>(
            (const unsigned short*)d_ws, locations, offset, loc_pred,
            out, out + deform_elems);
    } else {
        deform_gather_direct<<<(NPTOT + 3) / 4, 256, 0, stream>>>(
            feat, locations, offset, out);
        boxes_kernel<<<(NBOX + 255) / 256, 256, 0, stream>>>(
            locations, offset, loc_pred, out + deform_elems);
    }
}